// Round 1
// 834.775 us; speedup vs baseline: 2.2851x; 2.2851x over previous
//
#include <hip/hip_runtime.h>

// Problem constants (fixed by setup_inputs: B=16, DEPTH=15, X=H=128)
#define HB 128
#define B_ 16
#define TDEPTH 15
#define NN 32767
#define NLEAF 16384
#define LEAF_START 16383

using f16   = _Float16;
using f16x4 = __attribute__((ext_vector_type(4))) _Float16;
using f16x8 = __attribute__((ext_vector_type(8))) _Float16;
using f32x4 = __attribute__((ext_vector_type(4))) float;

#define MFMA16(A, B, C) __builtin_amdgcn_mfma_f32_16x16x32_f16(A, B, C, 0, 0, 0)

__device__ __forceinline__ float sigm(float a) { return 1.0f / (1.0f + __expf(-a)); }
__device__ __forceinline__ float tanh_f(float a) { return 1.0f - 2.0f / (__expf(2.0f * a) + 1.0f); }

// Pre-split (hi/lo f16) weight fragments in MFMA operand layout.
// frag[((ks*NT + nt)*2 + p)*64 + lane] holds 8 f16:
//   W[ks*32 + 8*(lane>>4) + j][nt*16 + (lane&15)]   (j = 0..7)
// This is simultaneously the A-operand layout for W^T and coalesced (lane*16B).
__device__ f16x8 g_WwF[4 * 16 * 2 * 64];   // Ww  (128x256): 128 KB
__device__ f16x8 g_UfF[8 * 16 * 2 * 64];   // Ufw (256x256): 256 KB
__device__ f16x8 g_UhF[8 * 8 * 2 * 64];    // Uhw (256x128): 128 KB

__global__ __launch_bounds__(256)
void prep_kernel(const float* __restrict__ Ww, const float* __restrict__ Ufw,
                 const float* __restrict__ Uhw) {
    int e = blockIdx.x * 256 + threadIdx.x;   // 0..131071 = 32768 + 65536 + 32768
    const float* W; f16* dst; int N;
    if (e < 32768)      { W = Ww;  dst = (f16*)g_WwF; N = 256; }
    else if (e < 98304) { W = Ufw; dst = (f16*)g_UfF; N = 256; e -= 32768; }
    else                { W = Uhw; dst = (f16*)g_UhF; N = 128; e -= 98304; }
    int NT = N >> 4;
    int j = e & 7, ln = (e >> 3) & 63;
    int nt = (e >> 9) & (NT - 1);
    int ks = e >> (NT == 16 ? 13 : 12);
    int k = ks * 32 + ((ln >> 4) << 3) + j;
    int n = nt * 16 + (ln & 15);
    float v = W[k * N + n];
    f16 hi = (f16)v;
    f16 lo = (f16)(v - (float)hi);
    int fi = ((ks * NT + nt) * 2) * 512 + ln * 8 + j;
    dst[fi] = hi;          // part 0 (hi)
    dst[fi + 512] = lo;    // part 1 (lo)
}

// Leaf: h = (1 - sigmoid(I[:,:128])) * tanh(I[:,128:]),  I = x_leaf @ Ww + Wb.
// 32 leaf rows per block; f16x3 split MFMA (W^T as A, x^T as B -> D = I^T).
__global__ __launch_bounds__(256, 2)
void leaf_mfma(const float* __restrict__ x, const float* __restrict__ Wb,
               float* __restrict__ out) {
    __shared__ alignas(16) f16 Ah[32 * 128];
    __shared__ alignas(16) f16 Al[32 * 128];
    __shared__ alignas(16) float Tl[32 * 128];   // tanh half, f32
    int t = threadIdx.x, lane = t & 63, w = t >> 6;
    int v0 = blockIdx.x * 32;

    // Stage x tile (32x128 f32, contiguous rows) -> hi/lo f16, XOR-swizzled LDS
#pragma unroll
    for (int r = 0; r < 2; ++r) {
        int m = r * 16 + (t >> 4);
        int k0 = (t & 15) * 8;
        int vi = v0 + m;
        long row = (long)(vi >> 14) * NN + LEAF_START + (vi & (NLEAF - 1));
        const float* xr = x + row * HB;
        f32x4 a = *(const f32x4*)(xr + k0);
        f32x4 b = *(const f32x4*)(xr + k0 + 4);
        f16x8 hi, lo;
#pragma unroll
        for (int i = 0; i < 4; ++i) {
            f16 ha = (f16)a[i], hb2 = (f16)b[i];
            hi[i] = ha; hi[i + 4] = hb2;
            lo[i] = (f16)(a[i] - (float)ha);
            lo[i + 4] = (f16)(b[i] - (float)hb2);
        }
        int idx = m * 128 + (k0 ^ ((m & 7) << 3));
        *(f16x8*)&Ah[idx] = hi;
        *(f16x8*)&Al[idx] = lo;
    }
    __syncthreads();

    f32x4 acc[4][2];
#pragma unroll
    for (int i = 0; i < 4; ++i)
#pragma unroll
        for (int mt = 0; mt < 2; ++mt)
#pragma unroll
            for (int q = 0; q < 4; ++q) acc[i][mt][q] = 0.f;

#pragma unroll
    for (int ks = 0; ks < 4; ++ks) {
        f16x8 Bh[2], Bl[2];
#pragma unroll
        for (int mt = 0; mt < 2; ++mt) {
            int m = mt * 16 + (lane & 15);
            int k0 = ks * 32 + ((lane >> 4) << 3);
            int idx = m * 128 + (k0 ^ ((m & 7) << 3));
            Bh[mt] = *(const f16x8*)&Ah[idx];
            Bl[mt] = *(const f16x8*)&Al[idx];
        }
#pragma unroll
        for (int nt = 0; nt < 4; ++nt) {
            int ntg = w * 4 + nt;
            f16x8 Wh = g_WwF[((ks * 16 + ntg) * 2) * 64 + lane];
            f16x8 Wl = g_WwF[((ks * 16 + ntg) * 2 + 1) * 64 + lane];
#pragma unroll
            for (int mt = 0; mt < 2; ++mt) {
                acc[nt][mt] = MFMA16(Wh, Bh[mt], acc[nt][mt]);
                acc[nt][mt] = MFMA16(Wh, Bl[mt], acc[nt][mt]);
                acc[nt][mt] = MFMA16(Wl, Bh[mt], acc[nt][mt]);
            }
        }
    }

    // D[n][m]: n = 16*ntg + 4*(lane>>4) + jr (4 consecutive per lane), m = 16*mt + (lane&15)
    int lg = lane >> 4, li = lane & 15;
    if (w >= 2) {   // n in [128,256): tanh half -> LDS (swizzled f32)
#pragma unroll
        for (int nt = 0; nt < 4; ++nt) {
            int n0 = (w * 4 + nt) * 16 + lg * 4;
            f32x4 bias = *(const f32x4*)&Wb[n0];
#pragma unroll
            for (int mt = 0; mt < 2; ++mt) {
                int m = mt * 16 + li;
                f32x4 tv;
#pragma unroll
                for (int jr = 0; jr < 4; ++jr) tv[jr] = tanh_f(acc[nt][mt][jr] + bias[jr]);
                int c0 = n0 - 128;
                *(f32x4*)&Tl[m * 128 + (c0 ^ ((m & 7) << 2))] = tv;
            }
        }
    }
    __syncthreads();
    if (w < 2) {    // n in [0,128): sigmoid half; combine + store
#pragma unroll
        for (int nt = 0; nt < 4; ++nt) {
            int n0 = (w * 4 + nt) * 16 + lg * 4;
            f32x4 bias = *(const f32x4*)&Wb[n0];
#pragma unroll
            for (int mt = 0; mt < 2; ++mt) {
                int m = mt * 16 + li;
                f32x4 tv = *(const f32x4*)&Tl[m * 128 + (n0 ^ ((m & 7) << 2))];
                f32x4 hv;
#pragma unroll
                for (int jr = 0; jr < 4; ++jr)
                    hv[jr] = (1.f - sigm(acc[nt][mt][jr] + bias[jr])) * tv[jr];
                int vi = v0 + m;
                long row = (long)(vi >> 14) * NN + LEAF_START + (vi & (NLEAF - 1));
                *(f32x4*)&out[row * HB + n0] = hv;
            }
        }
    }
}

// Internal level (fused): F = sigm(HC@Ufw+b); G = F.*HC; C = tanh(G@Uhw+b);
// h_new = (1-f1-f2)*C + f1*h1 + f2*h2.  32 (batch,node) virtual rows per block.
__global__ __launch_bounds__(256, 2)
void level_mfma(const float* __restrict__ Ufb, const float* __restrict__ Uhb,
                const float* __restrict__ h, float* __restrict__ hout, int l) {
    const int cnt = 1 << l, start = cnt - 1, total = B_ << l;
    __shared__ alignas(16) f16 Ah[32 * 256];   // HC hi, then G hi
    __shared__ alignas(16) f16 Al[32 * 256];   // HC lo, then G lo
    __shared__ alignas(16) float Fl[32 * 256]; // F (f32, for combine)
    int t = threadIdx.x, lane = t & 63, w = t >> 6;
    int v0 = blockIdx.x * 32;

    auto crow = [&](int vi) -> long {          // first child row of virtual node vi
        int bb = vi >> l, ii = vi - (bb << l);
        return (long)bb * NN + 2 * start + 1 + 2 * ii;
    };

    // Stage HC (32 x 256 f32; the two children rows are adjacent) -> hi/lo LDS
#pragma unroll
    for (int r = 0; r < 4; ++r) {
        int m = r * 8 + (t >> 5);
        int k0 = (t & 31) * 8;
        int vi = v0 + m; if (vi > total - 1) vi = total - 1;
        const float* hr = h + crow(vi) * HB;
        f32x4 a = *(const f32x4*)(hr + k0);
        f32x4 b = *(const f32x4*)(hr + k0 + 4);
        f16x8 hi, lo;
#pragma unroll
        for (int i = 0; i < 4; ++i) {
            f16 ha = (f16)a[i], hb2 = (f16)b[i];
            hi[i] = ha; hi[i + 4] = hb2;
            lo[i] = (f16)(a[i] - (float)ha);
            lo[i + 4] = (f16)(b[i] - (float)hb2);
        }
        int idx = m * 256 + (k0 ^ ((m & 7) << 3));
        *(f16x8*)&Ah[idx] = hi;
        *(f16x8*)&Al[idx] = lo;
    }
    __syncthreads();

    // GEMM1: D = Ufw^T * HC^T = F_pre^T; wave w owns n-tiles 4w..4w+3
    f32x4 acc[4][2];
#pragma unroll
    for (int i = 0; i < 4; ++i)
#pragma unroll
        for (int mt = 0; mt < 2; ++mt)
#pragma unroll
            for (int q = 0; q < 4; ++q) acc[i][mt][q] = 0.f;

#pragma unroll
    for (int ks = 0; ks < 8; ++ks) {
        f16x8 Bh[2], Bl[2];
#pragma unroll
        for (int mt = 0; mt < 2; ++mt) {
            int m = mt * 16 + (lane & 15);
            int k0 = ks * 32 + ((lane >> 4) << 3);
            int idx = m * 256 + (k0 ^ ((m & 7) << 3));
            Bh[mt] = *(const f16x8*)&Ah[idx];
            Bl[mt] = *(const f16x8*)&Al[idx];
        }
#pragma unroll
        for (int nt = 0; nt < 4; ++nt) {
            int ntg = w * 4 + nt;
            f16x8 Wh = g_UfF[((ks * 16 + ntg) * 2) * 64 + lane];
            f16x8 Wl = g_UfF[((ks * 16 + ntg) * 2 + 1) * 64 + lane];
#pragma unroll
            for (int mt = 0; mt < 2; ++mt) {
                acc[nt][mt] = MFMA16(Wh, Bh[mt], acc[nt][mt]);
                acc[nt][mt] = MFMA16(Wh, Bl[mt], acc[nt][mt]);
                acc[nt][mt] = MFMA16(Wl, Bh[mt], acc[nt][mt]);
            }
        }
    }
    __syncthreads();   // all GEMM1 LDS reads done before G overwrites Ah/Al

    // Epilogue 1: F = sigm(D+b); G = F.*HC (split hi/lo into Ah/Al); F -> Fl (f32)
    int lg = lane >> 4, li = lane & 15;
#pragma unroll
    for (int nt = 0; nt < 4; ++nt) {
        int n0 = (w * 4 + nt) * 16 + lg * 4;
        f32x4 bias = *(const f32x4*)&Ufb[n0];
#pragma unroll
        for (int mt = 0; mt < 2; ++mt) {
            int m = mt * 16 + li;
            int vi = v0 + m; if (vi > total - 1) vi = total - 1;
            const float* hr = h + crow(vi) * HB;
            f32x4 hcv = *(const f32x4*)(hr + n0);   // cache-hot re-read
            f32x4 fv;
            f16x4 gh, gl;
#pragma unroll
            for (int jr = 0; jr < 4; ++jr) {
                float f = sigm(acc[nt][mt][jr] + bias[jr]);
                fv[jr] = f;
                float g = f * hcv[jr];
                f16 g1 = (f16)g;
                gh[jr] = g1;
                gl[jr] = (f16)(g - (float)g1);
            }
            *(f32x4*)&Fl[m * 256 + (n0 ^ ((m & 7) << 2))] = fv;
            int ia = m * 256 + (n0 ^ ((m & 7) << 3));
            *(f16x4*)&Ah[ia] = gh;
            *(f16x4*)&Al[ia] = gl;
        }
    }
    __syncthreads();

    // GEMM2: D2 = Uhw^T * G^T = Cand_pre^T; wave w owns n-tiles 2w..2w+1 (N=128)
    f32x4 acc2[2][2];
#pragma unroll
    for (int i = 0; i < 2; ++i)
#pragma unroll
        for (int mt = 0; mt < 2; ++mt)
#pragma unroll
            for (int q = 0; q < 4; ++q) acc2[i][mt][q] = 0.f;

#pragma unroll
    for (int ks = 0; ks < 8; ++ks) {
        f16x8 Bh[2], Bl[2];
#pragma unroll
        for (int mt = 0; mt < 2; ++mt) {
            int m = mt * 16 + (lane & 15);
            int k0 = ks * 32 + ((lane >> 4) << 3);
            int idx = m * 256 + (k0 ^ ((m & 7) << 3));
            Bh[mt] = *(const f16x8*)&Ah[idx];
            Bl[mt] = *(const f16x8*)&Al[idx];
        }
#pragma unroll
        for (int nt = 0; nt < 2; ++nt) {
            int ntg = w * 2 + nt;
            f16x8 Wh = g_UhF[((ks * 8 + ntg) * 2) * 64 + lane];
            f16x8 Wl = g_UhF[((ks * 8 + ntg) * 2 + 1) * 64 + lane];
#pragma unroll
            for (int mt = 0; mt < 2; ++mt) {
                acc2[nt][mt] = MFMA16(Wh, Bh[mt], acc2[nt][mt]);
                acc2[nt][mt] = MFMA16(Wh, Bl[mt], acc2[nt][mt]);
                acc2[nt][mt] = MFMA16(Wl, Bh[mt], acc2[nt][mt]);
            }
        }
    }

    // Combine: h_new = (1-f1-f2)*tanh(D2+b) + f1*h1 + f2*h2
#pragma unroll
    for (int nt = 0; nt < 2; ++nt) {
        int c0 = (w * 2 + nt) * 16 + lg * 4;
        f32x4 bias = *(const f32x4*)&Uhb[c0];
#pragma unroll
        for (int mt = 0; mt < 2; ++mt) {
            int m = mt * 16 + li;
            int vi = v0 + m;
            int vic = vi > total - 1 ? total - 1 : vi;
            const float* hr = h + crow(vic) * HB;
            f32x4 h1 = *(const f32x4*)(hr + c0);
            f32x4 h2 = *(const f32x4*)(hr + c0 + 128);
            f32x4 f1 = *(const f32x4*)&Fl[m * 256 + (c0 ^ ((m & 7) << 2))];
            f32x4 f2 = *(const f32x4*)&Fl[m * 256 + ((c0 + 128) ^ ((m & 7) << 2))];
            f32x4 hn;
#pragma unroll
            for (int jr = 0; jr < 4; ++jr) {
                float cand = tanh_f(acc2[nt][mt][jr] + bias[jr]);
                hn[jr] = (1.f - f1[jr] - f2[jr]) * cand + f1[jr] * h1[jr] + f2[jr] * h2[jr];
            }
            if (vi < total) {
                int bb = vi >> l, ii = vi - (bb << l);
                long orow = (long)bb * NN + start + ii;
                *(f32x4*)&hout[orow * HB + c0] = hn;
            }
        }
    }
}

extern "C" void kernel_launch(void* const* d_in, const int* in_sizes, int n_in,
                              void* d_out, int out_size, void* d_ws, size_t ws_size,
                              hipStream_t stream) {
    (void)in_sizes; (void)n_in; (void)d_ws; (void)ws_size; (void)out_size;
    const float* x   = (const float*)d_in[0];
    const float* Ww  = (const float*)d_in[1];
    const float* Wb  = (const float*)d_in[2];
    const float* Ufw = (const float*)d_in[3];
    const float* Ufb = (const float*)d_in[4];
    const float* Uhw = (const float*)d_in[5];
    const float* Uhb = (const float*)d_in[6];
    float* out = (float*)d_out;

    // One-time (per launch) weight split/swizzle into device-global fragment buffers.
    prep_kernel<<<512, 256, 0, stream>>>(Ww, Ufw, Uhw);

    // Leaves (level 14): 16*16384/32 = 8192 blocks.
    leaf_mfma<<<B_ * NLEAF / 32, 256, 0, stream>>>(x, Wb, out);

    // Internal levels 13..0 (in-place: level-l writes are disjoint from child reads).
    for (int l = TDEPTH - 2; l >= 0; --l) {
        int total = B_ << l;
        int grid = (total + 31) / 32;
        level_mfma<<<grid, 256, 0, stream>>>(Ufb, Uhb, out, out, l);
    }
}

// Round 2
// 722.173 us; speedup vs baseline: 2.6414x; 1.1559x over previous
//
#include <hip/hip_runtime.h>

// Problem constants (fixed by setup_inputs: B=16, DEPTH=15, X=H=128)
#define HB 128
#define B_ 16
#define TDEPTH 15
#define NN 32767
#define NLEAF 16384
#define LEAF_START 16383

using f16   = _Float16;
using f16x4 = __attribute__((ext_vector_type(4))) _Float16;
using f16x8 = __attribute__((ext_vector_type(8))) _Float16;
using f32x4 = __attribute__((ext_vector_type(4))) float;

#define MFMA16(A, B, C) __builtin_amdgcn_mfma_f32_16x16x32_f16(A, B, C, 0, 0, 0)

__device__ __forceinline__ float sigm(float a) { return 1.0f / (1.0f + __expf(-a)); }
__device__ __forceinline__ float tanh_f(float a) { return 1.0f - 2.0f / (__expf(2.0f * a) + 1.0f); }

// Pre-split (hi/lo f16) weight fragments in MFMA operand layout.
// frag[((ks*NT + nt)*2 + p)*64 + lane] holds 8 f16:
//   W[ks*32 + 8*(lane>>4) + j][nt*16 + (lane&15)]   (j = 0..7)
// Simultaneously the A-operand layout for W^T and coalesced (lane*16B).
__device__ f16x8 g_WwF[4 * 16 * 2 * 64];   // Ww  (128x256): 128 KB
__device__ f16x8 g_UfF[8 * 16 * 2 * 64];   // Ufw (256x256): 256 KB
__device__ f16x8 g_UhF[8 * 8 * 2 * 64];    // Uhw (256x128): 128 KB

__global__ __launch_bounds__(256)
void prep_kernel(const float* __restrict__ Ww, const float* __restrict__ Ufw,
                 const float* __restrict__ Uhw) {
    int e = blockIdx.x * 256 + threadIdx.x;   // 0..131071 = 32768 + 65536 + 32768
    const float* W; f16* dst; int N;
    if (e < 32768)      { W = Ww;  dst = (f16*)g_WwF; N = 256; }
    else if (e < 98304) { W = Ufw; dst = (f16*)g_UfF; N = 256; e -= 32768; }
    else                { W = Uhw; dst = (f16*)g_UhF; N = 128; e -= 98304; }
    int NT = N >> 4;
    int j = e & 7, ln = (e >> 3) & 63;
    int nt = (e >> 9) & (NT - 1);
    int ks = e >> (NT == 16 ? 13 : 12);
    int k = ks * 32 + ((ln >> 4) << 3) + j;
    int n = nt * 16 + (ln & 15);
    float v = W[k * N + n];
    f16 hi = (f16)v;
    f16 lo = (f16)(v - (float)hi);
    int fi = ((ks * NT + nt) * 2) * 512 + ln * 8 + j;
    dst[fi] = hi;          // part 0 (hi)
    dst[fi + 512] = lo;    // part 1 (lo)
}

// Leaf: h = (1 - sigmoid(I[:,:128])) * tanh(I[:,128:]),  I = x_leaf @ Ww + Wb.
// 32 leaf rows per 512-thread block (8 waves); f16x3 split MFMA.
__global__ __launch_bounds__(512, 4)
void leaf_mfma(const float* __restrict__ x, const float* __restrict__ Wb,
               float* __restrict__ out) {
    __shared__ alignas(16) f16 Ah[32 * 128];
    __shared__ alignas(16) f16 Al[32 * 128];
    __shared__ alignas(16) float Tl[32 * 128];   // tanh half, f32
    int t = threadIdx.x, lane = t & 63, w = t >> 6;   // w in [0,8)
    int v0 = blockIdx.x * 32;

    // Stage x tile (32x128 f32, contiguous rows) -> hi/lo f16, XOR-swizzled LDS
    {
        int m = t >> 4;                // 0..31
        int k0 = (t & 15) * 8;         // 0..120
        int vi = v0 + m;
        long row = (long)(vi >> 14) * NN + LEAF_START + (vi & (NLEAF - 1));
        const float* xr = x + row * HB;
        f32x4 a = *(const f32x4*)(xr + k0);
        f32x4 b = *(const f32x4*)(xr + k0 + 4);
        f16x8 hi, lo;
#pragma unroll
        for (int i = 0; i < 4; ++i) {
            f16 ha = (f16)a[i], hb2 = (f16)b[i];
            hi[i] = ha; hi[i + 4] = hb2;
            lo[i] = (f16)(a[i] - (float)ha);
            lo[i + 4] = (f16)(b[i] - (float)hb2);
        }
        int idx = m * 128 + (k0 ^ ((m & 7) << 3));
        *(f16x8*)&Ah[idx] = hi;
        *(f16x8*)&Al[idx] = lo;
    }
    __syncthreads();

    // GEMM: wave w owns n-tiles 2w, 2w+1 (of 16)
    f32x4 acc[2][2];
#pragma unroll
    for (int i = 0; i < 2; ++i)
#pragma unroll
        for (int mt = 0; mt < 2; ++mt)
#pragma unroll
            for (int q = 0; q < 4; ++q) acc[i][mt][q] = 0.f;

#pragma unroll
    for (int ks = 0; ks < 4; ++ks) {
        f16x8 Bh[2], Bl[2];
#pragma unroll
        for (int mt = 0; mt < 2; ++mt) {
            int m = mt * 16 + (lane & 15);
            int k0 = ks * 32 + ((lane >> 4) << 3);
            int idx = m * 128 + (k0 ^ ((m & 7) << 3));
            Bh[mt] = *(const f16x8*)&Ah[idx];
            Bl[mt] = *(const f16x8*)&Al[idx];
        }
#pragma unroll
        for (int nt = 0; nt < 2; ++nt) {
            int ntg = w * 2 + nt;
            f16x8 Wh = g_WwF[((ks * 16 + ntg) * 2) * 64 + lane];
            f16x8 Wl = g_WwF[((ks * 16 + ntg) * 2 + 1) * 64 + lane];
#pragma unroll
            for (int mt = 0; mt < 2; ++mt) {
                acc[nt][mt] = MFMA16(Wh, Bh[mt], acc[nt][mt]);
                acc[nt][mt] = MFMA16(Wh, Bl[mt], acc[nt][mt]);
                acc[nt][mt] = MFMA16(Wl, Bh[mt], acc[nt][mt]);
            }
        }
    }

    // D[n][m]: n = 16*ntg + 4*(lane>>4) + jr, m = 16*mt + (lane&15)
    int lg = lane >> 4, li = lane & 15;
    if (w >= 4) {   // n in [128,256): tanh half -> LDS (swizzled f32)
#pragma unroll
        for (int nt = 0; nt < 2; ++nt) {
            int n0 = (w * 2 + nt) * 16 + lg * 4;
            f32x4 bias = *(const f32x4*)&Wb[n0];
#pragma unroll
            for (int mt = 0; mt < 2; ++mt) {
                int m = mt * 16 + li;
                f32x4 tv;
#pragma unroll
                for (int jr = 0; jr < 4; ++jr) tv[jr] = tanh_f(acc[nt][mt][jr] + bias[jr]);
                int c0 = n0 - 128;
                *(f32x4*)&Tl[m * 128 + (c0 ^ ((m & 7) << 2))] = tv;
            }
        }
    }
    __syncthreads();
    if (w < 4) {    // n in [0,128): sigmoid half; combine + store
#pragma unroll
        for (int nt = 0; nt < 2; ++nt) {
            int n0 = (w * 2 + nt) * 16 + lg * 4;
            f32x4 bias = *(const f32x4*)&Wb[n0];
#pragma unroll
            for (int mt = 0; mt < 2; ++mt) {
                int m = mt * 16 + li;
                f32x4 tv = *(const f32x4*)&Tl[m * 128 + (n0 ^ ((m & 7) << 2))];
                f32x4 hv;
#pragma unroll
                for (int jr = 0; jr < 4; ++jr)
                    hv[jr] = (1.f - sigm(acc[nt][mt][jr] + bias[jr])) * tv[jr];
                int vi = v0 + m;
                long row = (long)(vi >> 14) * NN + LEAF_START + (vi & (NLEAF - 1));
                *(f32x4*)&out[row * HB + n0] = hv;
            }
        }
    }
}

// Internal level (fused): F = sigm(HC@Ufw+b); G = F.*HC; C = tanh(G@Uhw+b);
// h_new = (1-f1-f2)*C + f1*h1 + f2*h2.  32 (batch,node) rows per 512-thread block.
__global__ __launch_bounds__(512, 4)
void level_mfma(const float* __restrict__ Ufb, const float* __restrict__ Uhb,
                const float* __restrict__ h, float* __restrict__ hout, int l) {
    const int start = (1 << l) - 1, total = B_ << l;
    __shared__ alignas(16) f16 Ah[32 * 256];   // HC hi, then G hi
    __shared__ alignas(16) f16 Al[32 * 256];   // HC lo, then G lo
    __shared__ alignas(16) float Fl[32 * 256]; // F (f32, for combine)
    int t = threadIdx.x, lane = t & 63, w = t >> 6;   // w in [0,8)
    int v0 = blockIdx.x * 32;

    auto crow = [&](int vi) -> long {          // first child row of virtual node vi
        int bb = vi >> l, ii = vi - (bb << l);
        return (long)bb * NN + 2 * start + 1 + 2 * ii;
    };

    // Stage HC (32 x 256 f32; two children rows adjacent) -> hi/lo LDS
#pragma unroll
    for (int r = 0; r < 2; ++r) {
        int m = r * 16 + (t >> 5);     // 0..31
        int k0 = (t & 31) * 8;         // 0..248
        int vi = v0 + m; if (vi > total - 1) vi = total - 1;
        const float* hr = h + crow(vi) * HB;
        f32x4 a = *(const f32x4*)(hr + k0);
        f32x4 b = *(const f32x4*)(hr + k0 + 4);
        f16x8 hi, lo;
#pragma unroll
        for (int i = 0; i < 4; ++i) {
            f16 ha = (f16)a[i], hb2 = (f16)b[i];
            hi[i] = ha; hi[i + 4] = hb2;
            lo[i] = (f16)(a[i] - (float)ha);
            lo[i + 4] = (f16)(b[i] - (float)hb2);
        }
        int idx = m * 256 + (k0 ^ ((m & 7) << 3));
        *(f16x8*)&Ah[idx] = hi;
        *(f16x8*)&Al[idx] = lo;
    }
    __syncthreads();

    // GEMM1: D = Ufw^T * HC^T = F_pre^T; wave w owns n-tiles 2w, 2w+1 (of 16)
    f32x4 acc[2][2];
#pragma unroll
    for (int i = 0; i < 2; ++i)
#pragma unroll
        for (int mt = 0; mt < 2; ++mt)
#pragma unroll
            for (int q = 0; q < 4; ++q) acc[i][mt][q] = 0.f;

#pragma unroll
    for (int ks = 0; ks < 8; ++ks) {
        f16x8 Bh[2], Bl[2];
#pragma unroll
        for (int mt = 0; mt < 2; ++mt) {
            int m = mt * 16 + (lane & 15);
            int k0 = ks * 32 + ((lane >> 4) << 3);
            int idx = m * 256 + (k0 ^ ((m & 7) << 3));
            Bh[mt] = *(const f16x8*)&Ah[idx];
            Bl[mt] = *(const f16x8*)&Al[idx];
        }
#pragma unroll
        for (int nt = 0; nt < 2; ++nt) {
            int ntg = w * 2 + nt;
            f16x8 Wh = g_UfF[((ks * 16 + ntg) * 2) * 64 + lane];
            f16x8 Wl = g_UfF[((ks * 16 + ntg) * 2 + 1) * 64 + lane];
#pragma unroll
            for (int mt = 0; mt < 2; ++mt) {
                acc[nt][mt] = MFMA16(Wh, Bh[mt], acc[nt][mt]);
                acc[nt][mt] = MFMA16(Wh, Bl[mt], acc[nt][mt]);
                acc[nt][mt] = MFMA16(Wl, Bh[mt], acc[nt][mt]);
            }
        }
    }
    __syncthreads();   // all GEMM1 LDS reads done before G overwrites Ah/Al

    // Epilogue 1: F = sigm(D+b); G = F.*HC (split hi/lo into Ah/Al); F -> Fl (f32)
    int lg = lane >> 4, li = lane & 15;
#pragma unroll
    for (int nt = 0; nt < 2; ++nt) {
        int n0 = (w * 2 + nt) * 16 + lg * 4;
        f32x4 bias = *(const f32x4*)&Ufb[n0];
#pragma unroll
        for (int mt = 0; mt < 2; ++mt) {
            int m = mt * 16 + li;
            int vi = v0 + m; if (vi > total - 1) vi = total - 1;
            const float* hr = h + crow(vi) * HB;
            f32x4 hcv = *(const f32x4*)(hr + n0);   // cache-hot re-read
            f32x4 fv;
            f16x4 gh, gl;
#pragma unroll
            for (int jr = 0; jr < 4; ++jr) {
                float f = sigm(acc[nt][mt][jr] + bias[jr]);
                fv[jr] = f;
                float g = f * hcv[jr];
                f16 g1 = (f16)g;
                gh[jr] = g1;
                gl[jr] = (f16)(g - (float)g1);
            }
            *(f32x4*)&Fl[m * 256 + (n0 ^ ((m & 7) << 2))] = fv;
            int ia = m * 256 + (n0 ^ ((m & 7) << 3));
            *(f16x4*)&Ah[ia] = gh;
            *(f16x4*)&Al[ia] = gl;
        }
    }
    __syncthreads();

    // GEMM2: D2 = Uhw^T * G^T = Cand_pre^T; wave w owns n-tile w (of 8, N=128)
    f32x4 acc2[2];
#pragma unroll
    for (int mt = 0; mt < 2; ++mt)
#pragma unroll
        for (int q = 0; q < 4; ++q) acc2[mt][q] = 0.f;

#pragma unroll
    for (int ks = 0; ks < 8; ++ks) {
        f16x8 Bh[2], Bl[2];
#pragma unroll
        for (int mt = 0; mt < 2; ++mt) {
            int m = mt * 16 + (lane & 15);
            int k0 = ks * 32 + ((lane >> 4) << 3);
            int idx = m * 256 + (k0 ^ ((m & 7) << 3));
            Bh[mt] = *(const f16x8*)&Ah[idx];
            Bl[mt] = *(const f16x8*)&Al[idx];
        }
        f16x8 Wh = g_UhF[((ks * 8 + w) * 2) * 64 + lane];
        f16x8 Wl = g_UhF[((ks * 8 + w) * 2 + 1) * 64 + lane];
#pragma unroll
        for (int mt = 0; mt < 2; ++mt) {
            acc2[mt] = MFMA16(Wh, Bh[mt], acc2[mt]);
            acc2[mt] = MFMA16(Wh, Bl[mt], acc2[mt]);
            acc2[mt] = MFMA16(Wl, Bh[mt], acc2[mt]);
        }
    }

    // Combine: h_new = (1-f1-f2)*tanh(D2+b) + f1*h1 + f2*h2
    {
        int c0 = w * 16 + lg * 4;
        f32x4 bias = *(const f32x4*)&Uhb[c0];
#pragma unroll
        for (int mt = 0; mt < 2; ++mt) {
            int m = mt * 16 + li;
            int vi = v0 + m;
            int vic = vi > total - 1 ? total - 1 : vi;
            const float* hr = h + crow(vic) * HB;
            f32x4 h1 = *(const f32x4*)(hr + c0);
            f32x4 h2 = *(const f32x4*)(hr + c0 + 128);
            f32x4 f1 = *(const f32x4*)&Fl[m * 256 + (c0 ^ ((m & 7) << 2))];
            f32x4 f2 = *(const f32x4*)&Fl[m * 256 + ((c0 + 128) ^ ((m & 7) << 2))];
            f32x4 hn;
#pragma unroll
            for (int jr = 0; jr < 4; ++jr) {
                float cand = tanh_f(acc2[mt][jr] + bias[jr]);
                hn[jr] = (1.f - f1[jr] - f2[jr]) * cand + f1[jr] * h1[jr] + f2[jr] * h2[jr];
            }
            if (vi < total) {
                int bb = vi >> l, ii = vi - (bb << l);
                long orow = (long)bb * NN + start + ii;
                *(f32x4*)&hout[orow * HB + c0] = hn;
            }
        }
    }
}

extern "C" void kernel_launch(void* const* d_in, const int* in_sizes, int n_in,
                              void* d_out, int out_size, void* d_ws, size_t ws_size,
                              hipStream_t stream) {
    (void)in_sizes; (void)n_in; (void)d_ws; (void)ws_size; (void)out_size;
    const float* x   = (const float*)d_in[0];
    const float* Ww  = (const float*)d_in[1];
    const float* Wb  = (const float*)d_in[2];
    const float* Ufw = (const float*)d_in[3];
    const float* Ufb = (const float*)d_in[4];
    const float* Uhw = (const float*)d_in[5];
    const float* Uhb = (const float*)d_in[6];
    float* out = (float*)d_out;

    // One-time (per launch) weight split/swizzle into device-global fragment buffers.
    prep_kernel<<<512, 256, 0, stream>>>(Ww, Ufw, Uhw);

    // Leaves (level 14): 16*16384/32 = 8192 blocks.
    leaf_mfma<<<B_ * NLEAF / 32, 512, 0, stream>>>(x, Wb, out);

    // Internal levels 13..0 (in-place: level-l writes disjoint from child reads).
    for (int l = TDEPTH - 2; l >= 0; --l) {
        int total = B_ << l;
        int grid = (total + 31) / 32;
        level_mfma<<<grid, 512, 0, stream>>>(Ufb, Uhb, out, out, l);
    }
}